// Round 9
// baseline (188.323 us; speedup 1.0000x reference)
//
#include <hip/hip_runtime.h>
#include <math.h>

#define B_    2
#define NB_   512
#define C_    80
#define FEAT_ 1024
#define FN_   128
#define FC_   128
#define PE_   64
#define G_    16
#define DQ_   64
#define EO_   8
#define NT_   3
#define SCALE_CLAMP_ 4.135166556742356f

typedef __attribute__((ext_vector_type(8))) short bf16x8;
typedef __attribute__((ext_vector_type(4))) float f32x4;

// ---- workspace layout (float offsets) ----
#define O_ROIP    ((size_t)0)                                   // 2*1024*128 (K-half partials)
#define O_RANKP   (O_ROIP + (size_t)2*B_*NB_*FC_)               // 2*128*128
#define O_RANKIDX (O_RANKP + (size_t)2*FN_*FC_)                 // B*128*80 (int)
#define O_SSCORE  (O_RANKIDX + (size_t)B_*FN_*C_)               // B*128*80
#define O_SBOX    (O_SSCORE + (size_t)B_*FN_*C_)                // B*128*80*4
#define O_EMB     (O_SBOX + (size_t)B_*FN_*C_*4)                // B*128*80*128
#define O_ATT     (O_EMB + (size_t)B_*FN_*C_*FC_)               // B*128*80*128
#define O_LW      (O_ATT + (size_t)B_*FN_*C_*FC_)               // 2*80*128*16*128 f16 = 84MB (stores log w)

__device__ __forceinline__ float bf2f(unsigned short u) {
    return __uint_as_float(((unsigned int)u) << 16);
}
__device__ __forceinline__ unsigned short f2bf(float f) {
    unsigned int x = __float_as_uint(f);
    unsigned int r = (x + 0x7fff + ((x >> 16) & 1)) >> 16;   // RNE
    return (unsigned short)r;
}
__device__ __forceinline__ unsigned short f2h(float x) {
    _Float16 h = (_Float16)x;
    return __builtin_bit_cast(unsigned short, h);
}
__device__ __forceinline__ float h2f(unsigned short u) {
    _Float16 h = __builtin_bit_cast(_Float16, u);
    return (float)h;
}

// 16B-granule swizzle, 128B row (8 granules)
#define ADDR128(row, gr)  ((row)*128 + ((((gr) ^ ((row)&7))) << 4))

// ============ embed GEMMs: roi (row-tiles 0..63) + rank (64..71), x2 K-halves ============
__global__ __launch_bounds__(256) void k_embed(const float* __restrict__ roi_feat,
                                               const float* __restrict__ roi_w,
                                               const float* __restrict__ roi_b,
                                               const float* __restrict__ rank_w,
                                               const float* __restrict__ rank_b,
                                               float* __restrict__ roiP,
                                               float* __restrict__ rankP)
{
    const int bid = blockIdx.x;
    const int kh  = bid & 1;
    const int rt  = bid >> 1;            // 0..71
    const bool isRank = rt >= 64;
    const int row0 = (isRank ? rt - 64 : rt) * 16;
    const int t = threadIdx.x;
    const int w = t >> 6, lane = t & 63, lr = lane & 15, lh = lane >> 4;
    const int col0 = w * 32;
    const float* W = isRank ? rank_w : roi_w;
    const float* bias = isRank ? rank_b : roi_b;

    const int arow = row0 + lr;
    f32x4 acc0 = {0,0,0,0}, acc1 = {0,0,0,0};

    #pragma unroll 4
    for (int ks = 0; ks < 16; ++ks) {
        const int kb = kh*512 + ks*32 + lh*8;
        bf16x8 af;
        if (!isRank) {
            float4 a0 = *(const float4*)(roi_feat + (size_t)arow*FEAT_ + kb);
            float4 a1 = *(const float4*)(roi_feat + (size_t)arow*FEAT_ + kb + 4);
            af[0] = (short)f2bf(a0.x); af[1] = (short)f2bf(a0.y);
            af[2] = (short)f2bf(a0.z); af[3] = (short)f2bf(a0.w);
            af[4] = (short)f2bf(a1.x); af[5] = (short)f2bf(a1.y);
            af[6] = (short)f2bf(a1.z); af[7] = (short)f2bf(a1.w);
        } else {
            #pragma unroll
            for (int j = 0; j < 8; ++j) {
                int k = kb + j;
                int kk = k & 511;
                float inv = exp2f(-(float)kk * 0.0194644226f);  // log2(1000)/512
                float arg = (float)arow * inv;
                float v = (k < 512) ? __sinf(arg) : __cosf(arg);
                af[j] = (short)f2bf(v);
            }
        }
        bf16x8 bf0, bf1;
        #pragma unroll
        for (int j = 0; j < 8; ++j) {
            const float* wr = W + (size_t)(kb + j)*FC_ + col0 + lr;
            bf0[j] = (short)f2bf(wr[0]);
            bf1[j] = (short)f2bf(wr[16]);
        }
        acc0 = __builtin_amdgcn_mfma_f32_16x16x32_bf16(af, bf0, acc0, 0, 0, 0);
        acc1 = __builtin_amdgcn_mfma_f32_16x16x32_bf16(af, bf1, acc1, 0, 0, 0);
    }
    float* dst = isRank ? (rankP + (size_t)kh*FN_*FC_) : (roiP + (size_t)kh*(B_*NB_)*FC_);
    #pragma unroll
    for (int tile = 0; tile < 2; ++tile) {
        f32x4 a = tile ? acc1 : acc0;
        int col = col0 + tile*16 + lr;
        float bv = (kh == 0) ? bias[col] : 0.0f;
        #pragma unroll
        for (int reg = 0; reg < 4; ++reg) {
            int rr = row0 + lh*4 + reg;
            dst[(size_t)rr*FC_ + col] = a[reg] + bv;
        }
    }
}

// ============ softmax over boxes + stable top-128 rank ============
__global__ __launch_bounds__(512) void k_topk(const float* __restrict__ scores,
                                              int* __restrict__ rank_idx,
                                              float* __restrict__ sorted_score)
{
    int b = blockIdx.x / C_, c = blockIdx.x % C_;
    __shared__ float p[NB_];
    __shared__ float red[NB_];
    int i = threadIdx.x;
    float s = scores[(size_t)(b*NB_ + i)*(C_+1) + c];
    red[i] = s; __syncthreads();
    for (int o = 256; o > 0; o >>= 1) { if (i < o) red[i] = fmaxf(red[i], red[i+o]); __syncthreads(); }
    float mx = red[0]; __syncthreads();
    float e = expf(s - mx);
    red[i] = e; __syncthreads();
    for (int o = 256; o > 0; o >>= 1) { if (i < o) red[i] += red[i+o]; __syncthreads(); }
    float sum = red[0]; __syncthreads();
    float pi = e / sum;
    p[i] = pi; __syncthreads();
    int rank = 0;
    for (int j4 = 0; j4 < NB_/4; ++j4) {
        float4 pj = *(const float4*)&p[j4*4];
        int j = j4*4;
        rank += (pj.x > pi) || (pj.x == pi && (j+0) < i);
        rank += (pj.y > pi) || (pj.y == pi && (j+1) < i);
        rank += (pj.z > pi) || (pj.z == pi && (j+2) < i);
        rank += (pj.w > pi) || (pj.w == pi && (j+3) < i);
    }
    if (rank < FN_) {
        rank_idx[(size_t)(b*FN_ + rank)*C_ + c] = i;
        sorted_score[(size_t)(b*FN_ + rank)*C_ + c] = pi;
    }
}

// ============ gather emb_feat (sum K-half partials) + refined boxes ============
__global__ __launch_bounds__(256) void k_gather(const int* __restrict__ rank_idx,
                                                const float* __restrict__ roiP,
                                                const float* __restrict__ rankP,
                                                const float* __restrict__ pdeltas,
                                                const float* __restrict__ pboxes,
                                                float* __restrict__ emb_feat,
                                                float* __restrict__ sorted_boxes)
{
    const int t = threadIdx.x;
    const int item = blockIdx.x*8 + (t >> 5);
    const int l = t & 31;
    const int c = item % C_;
    const int bn = item / C_;
    const int n = bn & (FN_-1);
    const int b = bn >> 7;
    const int idx = rank_idx[item];
    const int row = b*NB_ + idx;
    float4 e0 = *(const float4*)(roiP + (size_t)row*FC_ + l*4);
    float4 e1 = *(const float4*)(roiP + (size_t)(B_*NB_ + row)*FC_ + l*4);
    float4 r0 = *(const float4*)(rankP + (size_t)n*FC_ + l*4);
    float4 r1 = *(const float4*)(rankP + (size_t)(FN_ + n)*FC_ + l*4);
    *(float4*)(emb_feat + (size_t)item*FC_ + l*4) =
        make_float4(e0.x+e1.x+r0.x+r1.x, e0.y+e1.y+r0.y+r1.y,
                    e0.z+e1.z+r0.z+r1.z, e0.w+e1.w+r0.w+r1.w);
    if (l == 0) {
        float x1 = pboxes[row*4+0], y1 = pboxes[row*4+1], x2 = pboxes[row*4+2], y2 = pboxes[row*4+3];
        float w = x2 - x1, h = y2 - y1;
        float cx = x1 + 0.5f*w, cy = y1 + 0.5f*h;
        const float* dl = pdeltas + (size_t)row*(C_*4) + c*4;
        float dx = dl[0]/10.0f, dy = dl[1]/10.0f;
        float dw = fminf(dl[2]/5.0f, SCALE_CLAMP_);
        float dh = fminf(dl[3]/5.0f, SCALE_CLAMP_);
        float pcx = dx*w + cx, pcy = dy*h + cy;
        float pw = expf(dw)*w, ph = expf(dh)*h;
        float* ob = sorted_boxes + (size_t)item*4;
        ob[0] = pcx - 0.5f*pw; ob[1] = pcy - 0.5f*ph;
        ob[2] = pcx + 0.5f*pw; ob[3] = pcy + 0.5f*ph;
    }
}

// ============ prior via MFMA -> store f16(log w) ============
// grid: B*C*64 (2 n per block, 256 pairs), 256 threads.
// lw layout: [b*C+cl][n][g][m] f16 of log(clamp(relu(e@pos_w+pb),1e-6))
__global__ __launch_bounds__(256) void k_pos2(const float* __restrict__ sorted_boxes,
                                              const float* __restrict__ pos_w,
                                              const float* __restrict__ pos_b,
                                              unsigned short* __restrict__ lw)
{
    const int n2   = blockIdx.x & 63;
    const int rest = blockIdx.x >> 6;
    const int cl   = rest % C_;
    const int b    = rest / C_;
    const int n0   = n2 * 2;
    const int t    = threadIdx.x;

    __shared__ float geomL[FN_][6];               // 3 KB
    __shared__ unsigned short featL[256*PE_];     // 32 KB, swizzled 128B rows
    __shared__ unsigned short poswL[G_*PE_];      // 2 KB, swizzled 128B rows
    __shared__ float pbL[G_];
    __shared__ float sdimL[8];

    // ---- staging
    if (t < FN_) {
        const float* bx = sorted_boxes + (((size_t)(b*FN_ + t))*C_ + cl)*4;
        float x1 = bx[0], y1 = bx[1], x2 = bx[2], y2 = bx[3];
        float w = x2 - x1 + 1.0f;
        float h = y2 - y1 + 1.0f;
        geomL[t][0] = 0.5f*(x1+x2);
        geomL[t][1] = 0.5f*(y1+y2);
        geomL[t][2] = w;
        geomL[t][3] = h;
        geomL[t][4] = __logf(w);
        geomL[t][5] = __logf(h);
    } else {
        int id = t - 128;
        int g  = id >> 3;
        int gr = id & 7;
        unsigned short u[8];
        #pragma unroll
        for (int j = 0; j < 8; ++j) u[j] = f2bf(pos_w[(gr*8 + j)*G_ + g]);
        *(uint4*)((char*)poswL + ADDR128(g, gr)) =
            make_uint4((unsigned)u[0] | ((unsigned)u[1] << 16),
                       (unsigned)u[2] | ((unsigned)u[3] << 16),
                       (unsigned)u[4] | ((unsigned)u[5] << 16),
                       (unsigned)u[6] | ((unsigned)u[7] << 16));
    }
    if (t < G_) pbL[t] = pos_b[t];
    if (t >= 16 && t < 24) sdimL[t-16] = 1.0f / powf(1000.0f, 0.125f*(float)(t-16));
    __syncthreads();

    // ---- features: thread t = pair (n_local = t>>7, m = t&127)
    {
        const int nl = t >> 7;
        const int m  = t & 127;
        const int n  = n0 + nl;
        float pm[4];
        {
            float cxn = geomL[n][0], cyn = geomL[n][1];
            float rwn = 1.0f/geomL[n][2], rhn = 1.0f/geomL[n][3];
            pm[0] = __logf(fmaxf(fabsf((cxn - geomL[m][0]) * rwn), 1e-3f)) * 100.0f;
            pm[1] = __logf(fmaxf(fabsf((cyn - geomL[m][1]) * rhn), 1e-3f)) * 100.0f;
            pm[2] = (geomL[n][4] - geomL[m][4]) * 100.0f;
            pm[3] = (geomL[n][5] - geomL[m][5]) * 100.0f;
        }
        char* base = (char*)featL;
        #pragma unroll
        for (int f = 0; f < 4; ++f) {
            float s[8], c[8];
            #pragma unroll
            for (int r = 0; r < 8; ++r) {
                __sincosf(pm[f] * sdimL[r], &s[r], &c[r]);
            }
            unsigned short us[8], uc[8];
            #pragma unroll
            for (int r = 0; r < 8; ++r) { us[r] = f2bf(s[r]); uc[r] = f2bf(c[r]); }
            *(uint4*)(base + ADDR128(t, 2*f)) =
                make_uint4((unsigned)us[0] | ((unsigned)us[1] << 16),
                           (unsigned)us[2] | ((unsigned)us[3] << 16),
                           (unsigned)us[4] | ((unsigned)us[5] << 16),
                           (unsigned)us[6] | ((unsigned)us[7] << 16));
            *(uint4*)(base + ADDR128(t, 2*f + 1)) =
                make_uint4((unsigned)uc[0] | ((unsigned)uc[1] << 16),
                           (unsigned)uc[2] | ((unsigned)uc[3] << 16),
                           (unsigned)uc[4] | ((unsigned)uc[5] << 16),
                           (unsigned)uc[6] | ((unsigned)uc[7] << 16));
        }
    }
    __syncthreads();

    // ---- MFMA: 16 tiles of 16 pairs x 16 g, K=64
    {
        const int wave = t >> 6, lane = t & 63;
        const int lr = lane & 15, lh = lane >> 4;
        const float pbg = pbL[lr];           // g = lr
        #pragma unroll
        for (int ti = 0; ti < 4; ++ti) {
            const int t16 = wave*4 + ti;
            f32x4 acc = {0,0,0,0};
            #pragma unroll
            for (int ks = 0; ks < 2; ++ks) {
                bf16x8 a  = *(const bf16x8*)((char*)featL + ADDR128(t16*16 + lr, ks*4 + lh));
                bf16x8 bb = *(const bf16x8*)((char*)poswL + ADDR128(lr, ks*4 + lh));
                acc = __builtin_amdgcn_mfma_f32_16x16x32_bf16(a, bb, acc, 0, 0, 0);
            }
            const int g = lr;
            #pragma unroll
            for (int reg = 0; reg < 4; ++reg) {
                int p = t16*16 + lh*4 + reg;
                int n = n0 + (p >> 7);
                int m = p & 127;
                float w = fmaxf(fmaxf(acc[reg] + pbg, 0.0f), 1e-6f);
                lw[(((size_t)(b*C_ + cl)*FN_ + n)*G_ + g)*FN_ + m] = f2h(__logf(w));
            }
        }
    }
}

// ============ MFMA attention per (batch, class, group) — 70.5 KB LDS, 2 blocks/CU ============
// region FT (34816 B, rows stride 272B): ft bf16 -> aff f16 -> P bf16
#define FT_OFF   0
#define QL_OFF   34816    // q bf16 [128n][64dq] swz 16 KB
#define KL_OFF   51200    // k bf16 [128m][64dq] swz 16 KB
#define VT_OFF   67584    // V'^T bf16 [16e][128m] swz 4 KB
#define BIAS_OFF 71680    // 128 f32
#define SMEM_SZ  72192

__global__ __launch_bounds__(1024, 8) void k_attn(const float* __restrict__ emb_feat,
                                               const float* __restrict__ q_w, const float* __restrict__ q_b,
                                               const float* __restrict__ k_w, const float* __restrict__ k_b,
                                               const float* __restrict__ out_w, const float* __restrict__ out_b,
                                               const unsigned short* __restrict__ lw,
                                               float* __restrict__ att)
{
    const int g    = blockIdx.x & 15;
    const int rest = blockIdx.x >> 4;
    const int cl   = rest % C_;
    const int b    = rest / C_;
    const int c    = cl;
    const int t  = threadIdx.x;
    const int wave = t >> 6;
    const int lane = t & 63;
    const int lr = lane & 15;
    const int lh = lane >> 4;              // 0..3

    __shared__ char smem[SMEM_SZ];
    float* biasL = (float*)(smem + BIAS_OFF);

    // ================= P0: staging (ft + VT-zero + bias) =================
    for (int s = 0; s < 4; ++s) {
        int fi = t + s*1024;
        int n  = fi >> 5;
        int d4 = (fi & 31) << 2;
        float4 v = *(const float4*)(emb_feat + ((size_t)(b*FN_ + n)*C_ + c)*FC_ + d4);
        char* dst = smem + FT_OFF + n*272 + (fi & 31)*8;
        *(uint2*)dst = make_uint2((unsigned)f2bf(v.x) | ((unsigned)f2bf(v.y) << 16),
                                  (unsigned)f2bf(v.z) | ((unsigned)f2bf(v.w) << 16));
    }
    if (t >= 512 && t < 768) {
        int i = t - 512;
        *(uint2*)(smem + VT_OFF + 8*256 + i*8) = make_uint2(0u, 0u);
    }
    if (t >= 128 && t < 256) {
        int r = t - 128;
        biasL[r] = (r < 64) ? q_b[g*DQ_ + r] : k_b[g*DQ_ + (r-64)];
    }
    __syncthreads();

    // ================= P1: proj MFMA (A direct from global) =================
    {
        const int rb = (wave >> 2) * 32;
        const int nb = (wave & 3) * 32;
        const float* wsrc = (rb < 64) ? q_w : k_w;
        const int col0 = g*DQ_ + (rb & 63) + lr;
        f32x4 acc00 = {0,0,0,0}, acc01 = {0,0,0,0}, acc10 = {0,0,0,0}, acc11 = {0,0,0,0};
        f32x4 accV  = {0,0,0,0};
        #pragma unroll
        for (int ks = 0; ks < 4; ++ks) {
            const int k0 = ks*32 + lh*8;
            bf16x8 a0, a1;
            #pragma unroll
            for (int j = 0; j < 8; ++j) {
                const float* kp = wsrc + (size_t)(k0 + j)*1024;
                a0[j] = (short)f2bf(kp[col0]);
                a1[j] = (short)f2bf(kp[col0 + 16]);
            }
            const int fo = ks*64 + lh*16;
            bf16x8 b0 = *(const bf16x8*)(smem + FT_OFF + (nb + lr)*272 + fo);
            bf16x8 b1 = *(const bf16x8*)(smem + FT_OFF + (nb + 16 + lr)*272 + fo);
            acc00 = __builtin_amdgcn_mfma_f32_16x16x32_bf16(a0, b0, acc00, 0, 0, 0);
            acc01 = __builtin_amdgcn_mfma_f32_16x16x32_bf16(a0, b1, acc01, 0, 0, 0);
            acc10 = __builtin_amdgcn_mfma_f32_16x16x32_bf16(a1, b0, acc10, 0, 0, 0);
            acc11 = __builtin_amdgcn_mfma_f32_16x16x32_bf16(a1, b1, acc11, 0, 0, 0);
            if (wave < 8) {
                bf16x8 av;
                #pragma unroll
                for (int j = 0; j < 8; ++j)
                    av[j] = (lr < 8) ? (short)f2bf(out_w[(size_t)g*1024 + (size_t)(k0 + j)*8 + lr]) : (short)0;
                bf16x8 bv = *(const bf16x8*)(smem + FT_OFF + (wave*16 + lr)*272 + fo);
                accV = __builtin_amdgcn_mfma_f32_16x16x32_bf16(av, bv, accV, 0, 0, 0);
            }
        }
        #pragma unroll
        for (int ti = 0; ti < 2; ++ti) {
            #pragma unroll
            for (int tj = 0; tj < 2; ++tj) {
                f32x4 a = (ti == 0) ? (tj == 0 ? acc00 : acc01) : (tj == 0 ? acc10 : acc11);
                int r0 = rb + ti*16 + lh*4;
                int n  = nb + tj*16 + lr;
                float v0 = a[0] + biasL[r0+0];
                float v1 = a[1] + biasL[r0+1];
                float v2 = a[2] + biasL[r0+2];
                float v3 = a[3] + biasL[r0+3];
                int dq0 = r0 & 63;
                int off = (r0 < 64 ? QL_OFF : KL_OFF);
                char* dst = smem + off + ADDR128(n, dq0 >> 3) + ((dq0 >> 2) & 1)*8;
                *(uint2*)dst = make_uint2((unsigned)f2bf(v0) | ((unsigned)f2bf(v1) << 16),
                                          (unsigned)f2bf(v2) | ((unsigned)f2bf(v3) << 16));
            }
        }
        if (wave < 8 && lh < 2) {
            int m = wave*16 + lr;
            #pragma unroll
            for (int reg = 0; reg < 4; ++reg) {
                int e = lh*4 + reg;
                char* dst = smem + VT_OFF + (e)*256 + ((((m >> 3) ^ e)) << 4) + (m & 7)*2;
                *(unsigned short*)dst = f2bf(accV[reg]);
            }
        }
    }
    __syncthreads();

    // ================= P2: aff MFMA -> f16 into FT region (ft is dead) =================
    {
        const int nb = (wave >> 2) * 32;
        const int mb = (wave & 3) * 32;
        f32x4 acc00 = {0,0,0,0}, acc01 = {0,0,0,0}, acc10 = {0,0,0,0}, acc11 = {0,0,0,0};
        #pragma unroll
        for (int ks = 0; ks < 2; ++ks) {
            int soff = ((ks*4 + lh) ^ (lr & 7)) << 4;
            bf16x8 a0 = *(const bf16x8*)(smem + QL_OFF + (nb + lr)*128 + soff);
            bf16x8 a1 = *(const bf16x8*)(smem + QL_OFF + (nb + 16 + lr)*128 + soff);
            bf16x8 b0 = *(const bf16x8*)(smem + KL_OFF + (mb + lr)*128 + soff);
            bf16x8 b1 = *(const bf16x8*)(smem + KL_OFF + (mb + 16 + lr)*128 + soff);
            acc00 = __builtin_amdgcn_mfma_f32_16x16x32_bf16(a0, b0, acc00, 0, 0, 0);
            acc01 = __builtin_amdgcn_mfma_f32_16x16x32_bf16(a0, b1, acc01, 0, 0, 0);
            acc10 = __builtin_amdgcn_mfma_f32_16x16x32_bf16(a1, b0, acc10, 0, 0, 0);
            acc11 = __builtin_amdgcn_mfma_f32_16x16x32_bf16(a1, b1, acc11, 0, 0, 0);
        }
        #pragma unroll
        for (int ti = 0; ti < 2; ++ti) {
            #pragma unroll
            for (int tj = 0; tj < 2; ++tj) {
                f32x4 a = (ti == 0) ? (tj == 0 ? acc00 : acc01) : (tj == 0 ? acc10 : acc11);
                int n0 = nb + ti*16 + lh*4;
                int m  = mb + tj*16 + lr;
                #pragma unroll
                for (int reg = 0; reg < 4; ++reg)
                    *(unsigned short*)(smem + FT_OFF + (n0 + reg)*272 + 2*m) = f2h(a[reg]);
            }
        }
    }
    __syncthreads();

    // ================= P3: softmax (aff f16 + lw f16, vectorized) -> P bf16 in place =================
    {
        const int row = t >> 3;
        const int lp  = t & 7;
        const int m0  = lp * 16;
        const unsigned short* lwrow = lw + ((((size_t)(b*C_ + cl))*FN_ + row)*G_ + g)*FN_ + m0;
        uint4 gl0 = *(const uint4*)(lwrow);
        uint4 gl1 = *(const uint4*)(lwrow + 8);
        char* abase = smem + FT_OFF + row*272 + lp*32;
        uint4 af0 = *(const uint4*)abase;
        uint4 af1 = *(const uint4*)(abase + 16);
        const unsigned short* ah0 = (const unsigned short*)&af0;
        const unsigned short* ah1 = (const unsigned short*)&af1;
        const unsigned short* lp0 = (const unsigned short*)&gl0;
        const unsigned short* lp1 = (const unsigned short*)&gl1;
        float v[16];
        float mx = -INFINITY;
        #pragma unroll
        for (int j = 0; j < 8; ++j) {
            float val = h2f(ah0[j])*0.125f + h2f(lp0[j]);
            v[j] = val; mx = fmaxf(mx, val);
        }
        #pragma unroll
        for (int j = 0; j < 8; ++j) {
            float val = h2f(ah1[j])*0.125f + h2f(lp1[j]);
            v[8+j] = val; mx = fmaxf(mx, val);
        }
        #pragma unroll
        for (int s = 1; s < 8; s <<= 1) mx = fmaxf(mx, __shfl_xor(mx, s, 8));
        float sum = 0.f;
        #pragma unroll
        for (int j = 0; j < 16; ++j) { v[j] = __expf(v[j] - mx); sum += v[j]; }
        #pragma unroll
        for (int s = 1; s < 8; s <<= 1) sum += __shfl_xor(sum, s, 8);
        float rs = 1.0f / sum;
        unsigned short u[16];
        #pragma unroll
        for (int j = 0; j < 16; ++j) u[j] = f2bf(v[j] * rs);
        *(uint4*)abase = make_uint4((unsigned)u[0] | ((unsigned)u[1] << 16),
                                    (unsigned)u[2] | ((unsigned)u[3] << 16),
                                    (unsigned)u[4] | ((unsigned)u[5] << 16),
                                    (unsigned)u[6] | ((unsigned)u[7] << 16));
        *(uint4*)(abase + 16) = make_uint4((unsigned)u[8]  | ((unsigned)u[9]  << 16),
                                           (unsigned)u[10] | ((unsigned)u[11] << 16),
                                           (unsigned)u[12] | ((unsigned)u[13] << 16),
                                           (unsigned)u[14] | ((unsigned)u[15] << 16));
    }
    __syncthreads();

    // ================= P4: att = P @ V' =================
    if (wave < 8) {
        const int tb = wave * 16;
        f32x4 acc = {0,0,0,0};
        #pragma unroll
        for (int ks = 0; ks < 4; ++ks) {
            const int fo = ks*64 + lh*16;
            int soff = ((ks*4 + lh) ^ lr) << 4;
            bf16x8 a = *(const bf16x8*)(smem + FT_OFF + (tb + lr)*272 + fo);
            bf16x8 bv = *(const bf16x8*)(smem + VT_OFF + lr*256 + soff);
            acc = __builtin_amdgcn_mfma_f32_16x16x32_bf16(a, bv, acc, 0, 0, 0);
        }
        if (lr < 8) {
            float ob = out_b[g*EO_ + lr];
            #pragma unroll
            for (int reg = 0; reg < 4; ++reg) {
                int n = tb + lh*4 + reg;
                att[((size_t)(b*FN_ + n)*C_ + c)*FC_ + g*EO_ + lr] = acc[reg] + ob;
            }
        }
    }
}

// ============ final: 8 items/block, 32 lanes/item ============
__global__ __launch_bounds__(256) void k_final(const float* __restrict__ emb_feat,
                                               const float* __restrict__ att,
                                               const float* __restrict__ logit_w,
                                               const float* __restrict__ logit_b,
                                               const float* __restrict__ sorted_score,
                                               float* __restrict__ out)
{
    __shared__ float lwL[FC_*NT_ + NT_];
    const int t = threadIdx.x;
    for (int i = t; i < FC_*NT_ + NT_; i += 256)
        lwL[i] = (i < FC_*NT_) ? logit_w[i] : logit_b[i - FC_*NT_];
    __syncthreads();
    const int item = blockIdx.x*8 + (t >> 5);
    const int l = t & 31;
    const int d0 = l*4;
    float4 ev = *(const float4*)(emb_feat + (size_t)item*FC_ + d0);
    float4 av = *(const float4*)(att + (size_t)item*FC_ + d0);
    float a0 = fmaxf(ev.x + av.x, 0.f);
    float a1 = fmaxf(ev.y + av.y, 0.f);
    float a2 = fmaxf(ev.z + av.z, 0.f);
    float a3 = fmaxf(ev.w + av.w, 0.f);
    float s0 = a0*lwL[(d0+0)*NT_+0] + a1*lwL[(d0+1)*NT_+0] + a2*lwL[(d0+2)*NT_+0] + a3*lwL[(d0+3)*NT_+0];
    float s1 = a0*lwL[(d0+0)*NT_+1] + a1*lwL[(d0+1)*NT_+1] + a2*lwL[(d0+2)*NT_+1] + a3*lwL[(d0+3)*NT_+1];
    float s2 = a0*lwL[(d0+0)*NT_+2] + a1*lwL[(d0+1)*NT_+2] + a2*lwL[(d0+2)*NT_+2] + a3*lwL[(d0+3)*NT_+2];
    #pragma unroll
    for (int s = 1; s < 32; s <<= 1) {
        s0 += __shfl_xor(s0, s, 32);
        s1 += __shfl_xor(s1, s, 32);
        s2 += __shfl_xor(s2, s, 32);
    }
    if (l < NT_) {
        float lg = (l == 0) ? s0 : (l == 1) ? s1 : s2;
        lg += lwL[FC_*NT_ + l];
        float sg = 1.f / (1.f + expf(-lg));
        out[(size_t)item*NT_ + l] = sg * sorted_score[item];
    }
}

extern "C" void kernel_launch(void* const* d_in, const int* in_sizes, int n_in,
                              void* d_out, int out_size, void* d_ws, size_t ws_size,
                              hipStream_t stream) {
    (void)in_sizes; (void)n_in; (void)out_size; (void)ws_size;
    const float* roi_feat = (const float*)d_in[0];
    const float* scores   = (const float*)d_in[1];
    const float* pdeltas  = (const float*)d_in[2];
    const float* pboxes   = (const float*)d_in[3];
    const float* roi_w    = (const float*)d_in[4];
    const float* roi_b    = (const float*)d_in[5];
    const float* rank_w   = (const float*)d_in[6];
    const float* rank_b   = (const float*)d_in[7];
    const float* logit_w  = (const float*)d_in[8];
    const float* logit_b  = (const float*)d_in[9];
    const float* pos_w    = (const float*)d_in[10];
    const float* pos_b    = (const float*)d_in[11];
    const float* q_w      = (const float*)d_in[12];
    const float* q_b      = (const float*)d_in[13];
    const float* k_w      = (const float*)d_in[14];
    const float* k_b      = (const float*)d_in[15];
    const float* out_w    = (const float*)d_in[16];
    const float* out_b    = (const float*)d_in[17];
    float* ws = (float*)d_ws;

    float* roiP         = ws + O_ROIP;
    float* rankP        = ws + O_RANKP;
    int*   rank_idx     = (int*)(ws + O_RANKIDX);
    float* sorted_score = ws + O_SSCORE;
    float* sorted_boxes = ws + O_SBOX;
    float* emb_feat     = ws + O_EMB;
    float* att          = ws + O_ATT;
    unsigned short* lwb = (unsigned short*)(ws + O_LW);

    k_embed<<<dim3(144), dim3(256), 0, stream>>>(roi_feat, roi_w, roi_b, rank_w, rank_b,
                                                 roiP, rankP);
    k_topk<<<dim3(B_*C_), dim3(512), 0, stream>>>(scores, rank_idx, sorted_score);
    k_gather<<<dim3(B_*FN_*C_/8), dim3(256), 0, stream>>>(rank_idx, roiP, rankP,
                                                          pdeltas, pboxes, emb_feat, sorted_boxes);
    k_pos2<<<dim3(B_*C_*64), dim3(256), 0, stream>>>(sorted_boxes, pos_w, pos_b, lwb);
    k_attn<<<dim3(B_*C_*G_), dim3(1024), 0, stream>>>(emb_feat, q_w, q_b, k_w, k_b,
                                                      out_w, out_b, lwb, att);
    k_final<<<dim3(B_*FN_*C_/8), dim3(256), 0, stream>>>(emb_feat, att, logit_w, logit_b,
                                                         sorted_score, d_out ? (float*)d_out : nullptr);
}